// Round 6
// baseline (534.442 us; speedup 1.0000x reference)
//
#include <hip/hip_runtime.h>
#include <hip/hip_bf16.h>
#include <cstdint>
#include <cstddef>

#define S_TOK 2048
#define M_DIM 768
#define H_DIM 3072
#define E_NUM 16
#define CAP   256   // 2*S/E

using s16x8 = __attribute__((ext_vector_type(8))) short;  // 8 bf16 (4 VGPRs)
using u16x8 = __attribute__((ext_vector_type(8))) unsigned short;
using f32x4 = __attribute__((ext_vector_type(4))) float;

__device__ __forceinline__ unsigned short f2bf(float f) {
    unsigned u = __float_as_uint(f);
    unsigned r = 0x7fffu + ((u >> 16) & 1u);
    return (unsigned short)((u + r) >> 16);
}

__device__ __forceinline__ void async16(const void* g, void* l) {
    __builtin_amdgcn_global_load_lds((const __attribute__((address_space(1))) void*)g,
                                     (__attribute__((address_space(3))) void*)l, 16, 0, 0);
}

// ---------------------------------------------------------------------------
// Kernel 1: gating + x->bf16 conversion fused (one wave per token).
// Wave tok==ntok only writes the bf16 zero row.
// ---------------------------------------------------------------------------
__global__ void gating_kernel(const float* __restrict__ x, const float* __restrict__ wg,
                              int* __restrict__ e1o, int* __restrict__ e2o,
                              float* __restrict__ g1o, float* __restrict__ g2o,
                              unsigned short* __restrict__ xb, int ntok) {
    int gid  = blockIdx.x * blockDim.x + threadIdx.x;
    int tok  = gid >> 6;
    int lane = threadIdx.x & 63;
    if (tok > ntok) return;
    unsigned short* xbr = xb + (size_t)tok * M_DIM;
    if (tok == ntok) {                       // appended zero row
        for (int m = lane; m < M_DIM; m += 64) xbr[m] = 0;
        return;
    }
    const float* xr = x + (size_t)tok * M_DIM;
    float acc[E_NUM];
#pragma unroll
    for (int e = 0; e < E_NUM; ++e) acc[e] = 0.f;
    for (int m = lane; m < M_DIM; m += 64) {
        float xv = xr[m];
        xbr[m] = f2bf(xv);                   // fused conversion
        const float* wr = wg + (size_t)m * E_NUM;
#pragma unroll
        for (int e = 0; e < E_NUM; ++e) acc[e] += xv * wr[e];
    }
#pragma unroll
    for (int off = 32; off >= 1; off >>= 1) {
#pragma unroll
        for (int e = 0; e < E_NUM; ++e) acc[e] += __shfl_xor(acc[e], off, 64);
    }
    if (lane == 0) {
        float mx = acc[0];
#pragma unroll
        for (int e = 1; e < E_NUM; ++e) mx = fmaxf(mx, acc[e]);
        float p[E_NUM]; float s = 0.f;
#pragma unroll
        for (int e = 0; e < E_NUM; ++e) { p[e] = expf(acc[e] - mx); s += p[e]; }
        float inv = 1.f / s;
        int b1 = 0; float v1 = -1.f;
#pragma unroll
        for (int e = 0; e < E_NUM; ++e) { if (p[e] > v1) { v1 = p[e]; b1 = e; } }
        int b2 = 0; float v2 = -1.f;
#pragma unroll
        for (int e = 0; e < E_NUM; ++e) { if (e != b1 && p[e] > v2) { v2 = p[e]; b2 = e; } }
        e1o[tok] = b1; e2o[tok] = b2;
        g1o[tok] = v1 * inv; g2o[tok] = v2 * inv;
    }
}

// ---------------------------------------------------------------------------
// Kernel 2: assignment — capacity positions via ballot prefix scan.
// ---------------------------------------------------------------------------
__global__ void assign_kernel(const int* __restrict__ e1a, const int* __restrict__ e2a,
                              const float* __restrict__ g1a, const float* __restrict__ g2a,
                              int* __restrict__ slot1, int* __restrict__ slot2,
                              float* __restrict__ w1, float* __restrict__ w2,
                              int* __restrict__ tfs, int G) {
    int g    = blockIdx.x;
    int tid  = threadIdx.x;
    int w    = tid >> 6;
    int lane = tid & 63;
    __shared__ int cnt1s[E_NUM];

    for (int i = tid; i < E_NUM * CAP; i += 1024) tfs[(size_t)g * E_NUM * CAP + i] = -1;
    __syncthreads();

    {
        int cnt = 0;
        for (int base = 0; base < S_TOK; base += 64) {
            int t = g * S_TOK + base + lane;
            bool pred = (e1a[t] == w);
            unsigned long long bal = __ballot(pred);
            int prefix = __popcll(bal & ((1ull << lane) - 1ull));
            if (pred) {
                int pos = cnt + prefix;
                if (pos < CAP) {
                    slot1[t] = w * CAP + pos;
                    tfs[((size_t)g * E_NUM + w) * CAP + pos] = base + lane;
                } else {
                    slot1[t] = -1;
                }
            }
            cnt += __popcll(bal);
        }
        if (lane == 0) cnt1s[w] = cnt < CAP ? cnt : CAP;
    }
    __syncthreads();
    {
        int cnt = cnt1s[w];
        for (int base = 0; base < S_TOK; base += 64) {
            int t = g * S_TOK + base + lane;
            bool pred = (e2a[t] == w);
            unsigned long long bal = __ballot(pred);
            int prefix = __popcll(bal & ((1ull << lane) - 1ull));
            if (pred) {
                int pos = cnt + prefix;
                if (pos < CAP) {
                    slot2[t] = w * CAP + pos;
                    tfs[((size_t)g * E_NUM + w) * CAP + pos] = base + lane;
                } else {
                    slot2[t] = -1;
                }
            }
            cnt += __popcll(bal);
        }
    }
    __syncthreads();
    for (int t = tid; t < S_TOK; t += 1024) {
        int gt = g * S_TOK + t;
        float a = slot1[gt] >= 0 ? g1a[gt] : 0.f;
        float b = slot2[gt] >= 0 ? g2a[gt] : 0.f;
        float denom = a + b;
        if (!(denom > 0.f)) denom = 1.f;
        w1[gt] = a / denom;
        w2[gt] = b / denom;
    }
}

// ---------------------------------------------------------------------------
// Kernel 3: fused transpose+convert for BOTH weights, VECTORIZED.
// wi [E][768][3072] -> wiT [E][3072][768]; wo [E][3072][768] -> woT [E][768][3072]
// Read: float4/lane (wave = 4x256B segments). LDS: float4 into [64][68] pad.
// Write: 2x ushort8 (16B)/lane; 4 lanes/output-row -> 128B contiguous segments.
// LDS read-out is 4-way conflicted (1.58x on ~90cyc) — hidden under HBM stream.
// ---------------------------------------------------------------------------
#define NB_WI ((H_DIM / 64) * (M_DIM / 64) * E_NUM)   // 48*12*16 = 9216
__global__ __launch_bounds__(256) void transpose_conv_kernel(const float* __restrict__ wi,
                                                             unsigned short* __restrict__ wiT,
                                                             const float* __restrict__ wo,
                                                             unsigned short* __restrict__ woT) {
    __shared__ float T[64][68];
    int bid = blockIdx.x;
    const float* src; unsigned short* dst; int R, C, cx, ry, e;
    if (bid < NB_WI) {
        int per = (H_DIM / 64) * (M_DIM / 64);   // 576
        e = bid / per; int rem = bid % per;
        cx = rem % (H_DIM / 64); ry = rem / (H_DIM / 64);
        R = M_DIM; C = H_DIM; src = wi; dst = wiT;
    } else {
        int b2 = bid - NB_WI;
        int per = (M_DIM / 64) * (H_DIM / 64);
        e = b2 / per; int rem = b2 % per;
        cx = rem % (M_DIM / 64); ry = rem / (M_DIM / 64);
        R = H_DIM; C = M_DIM; src = wo; dst = woT;
    }
    int c0 = cx * 64;
    int r0 = ry * 64;
    int tid = threadIdx.x;

    // ---- read phase: 4x float4 per thread, coalesced ----
    const float* Sp = src + (size_t)e * R * C + (size_t)r0 * C + c0;
    int rr = tid >> 4;           // 0..15
    int cq = (tid & 15) * 4;     // col quad within the 64-wide tile
#pragma unroll
    for (int p = 0; p < 4; ++p) {
        int row = p * 16 + rr;
        float4 v = *(const float4*)&Sp[(size_t)row * C + cq];
        *(float4*)&T[row][cq] = v;
    }
    __syncthreads();

    // ---- write phase: 16 converts -> 2x ushort8 per thread ----
    unsigned short* D = dst + (size_t)e * C * R + (size_t)c0 * R + r0;
    int c  = tid >> 2;           // 0..63 output row (transposed)
    int rb = (tid & 3) * 16;     // 16-element run within the 64 output cols
    u16x8 o0, o1;
#pragma unroll
    for (int j = 0; j < 8; ++j) o0[j] = f2bf(T[rb + j][c]);
#pragma unroll
    for (int j = 0; j < 8; ++j) o1[j] = f2bf(T[rb + 8 + j][c]);
    *(u16x8*)&D[(size_t)c * R + rb]     = o0;
    *(u16x8*)&D[(size_t)c * R + rb + 8] = o1;
}

// ---------------------------------------------------------------------------
// Kernel 5: MFMA GEMM, 256x128 tile (M = full CAP), BK=32, 512 threads/8 waves,
// double-buffered (stage t+1 before computing t, one barrier per iter).
// Wave grid 2M x 4N: per-wave output 128x32 -> acc[8][2] f32x4 (64 VGPR).
//
// Grid 1-D, XCD-chunked remap; logical order (outer->inner): e, kh, n, g.
// ---------------------------------------------------------------------------
template<int KLOOP, bool GATHER>
__global__ __launch_bounds__(512, 4) void mfma_gemm_kernel(
        const unsigned short* __restrict__ A,
        const unsigned short* __restrict__ B,
        const int* __restrict__ tfs,
        void* __restrict__ Out0, void* __restrict__ Out1,
        int G, int N_total, int kstride, int NKH) {
    __shared__ unsigned short As[2][256 * 32];   // 32 KB
    __shared__ unsigned short Bs[2][128 * 32];   // 16 KB
    __shared__ int rowtok[256];

    // ---- block remap (bijective; NB % 8 == 0) ----
    int NB  = gridDim.x;
    int bid = blockIdx.x;
    int per = NB >> 3;
    int lid = (bid & 7) * per + (bid >> 3);

    int NT_N = N_total >> 7;        // n-tiles of 128
    int g  = lid % G;
    int r1 = lid / G;
    int n  = r1 % NT_N;
    int r2 = r1 / NT_N;
    int kh = r2 % NKH;
    int e  = r2 / NKH;
    int z  = e * G + g;
    int n0 = n * 128;
    int koff = kh * KLOOP;
    int tid = threadIdx.x;

    if (GATHER) {
        if (tid < 256) rowtok[tid] = tfs[((size_t)g * E_NUM + e) * CAP + tid];
        __syncthreads();
    }

    int r8 = tid >> 2, l4 = tid & 3;    // r8: 0..127 staging row, l4: 16B chunk
    const unsigned short *apt0, *apt1, *bpt0;
    if (GATHER) {
        int t0 = rowtok[r8], t1 = rowtok[128 + r8];
        size_t row0 = (t0 < 0) ? (size_t)(G * S_TOK) : (size_t)(g * S_TOK + t0);
        size_t row1 = (t1 < 0) ? (size_t)(G * S_TOK) : (size_t)(g * S_TOK + t1);
        apt0 = A + row0 * kstride + koff + l4 * 8;
        apt1 = A + row1 * kstride + koff + l4 * 8;
    } else {
        apt0 = A + ((size_t)z * CAP + r8) * kstride + koff + l4 * 8;
        apt1 = apt0 + (size_t)128 * kstride;
    }
    bpt0 = B + ((size_t)e * N_total + n0 + r8) * kstride + koff + l4 * 8;

    int wv = tid >> 6;                  // 0..7
    int lane = tid & 63;
    int r = lane & 15, q = lane >> 4;
    int wm = wv & 1, wn = wv >> 1;      // 2M x 4N

    f32x4 acc[8][2];
#pragma unroll
    for (int i = 0; i < 8; ++i) {
        acc[i][0] = (f32x4)(0.f);
        acc[i][1] = (f32x4)(0.f);
    }

#define STAGE(b) do {                                      \
        async16(apt0, &As[b][(wv * 16) * 32]);             \
        async16(apt1, &As[b][(128 + wv * 16) * 32]);       \
        async16(bpt0, &Bs[b][(wv * 16) * 32]);             \
        apt0 += 32; apt1 += 32; bpt0 += 32;                \
    } while (0)

    const int NT = KLOOP / 32;
    STAGE(0);
    __syncthreads();          // tile 0 resident
    int cur = 0;
    for (int t = 0; t < NT; ++t) {
        if (t + 1 < NT) STAGE(cur ^ 1);     // issue next tile; hides under compute
        s16x8 bfr0 = *(const s16x8*)&Bs[cur][(wn * 32 + r) * 32 + q * 8];
        s16x8 bfr1 = *(const s16x8*)&Bs[cur][(wn * 32 + 16 + r) * 32 + q * 8];
#pragma unroll
        for (int i = 0; i < 8; ++i) {
            s16x8 af = *(const s16x8*)&As[cur][(wm * 128 + i * 16 + r) * 32 + q * 8];
            acc[i][0] = __builtin_amdgcn_mfma_f32_16x16x32_bf16(af, bfr0, acc[i][0], 0, 0, 0);
            acc[i][1] = __builtin_amdgcn_mfma_f32_16x16x32_bf16(af, bfr1, acc[i][1], 0, 0, 0);
        }
        __syncthreads();      // next tile resident; cur buffer free for restage
        cur ^= 1;
    }
#undef STAGE

    // epilogue
    if (GATHER) {
        unsigned short* H = (unsigned short*)Out0;  // [z][CAP][N_total]
#pragma unroll
        for (int i = 0; i < 8; ++i) {
#pragma unroll
            for (int v = 0; v < 4; ++v) {
                int m_loc = wm * 128 + i * 16 + q * 4 + v;
                unsigned short* row = H + ((size_t)z * CAP + m_loc) * N_total + n0 + wn * 32;
#pragma unroll
                for (int j = 0; j < 2; ++j) {
                    row[j * 16 + r] = f2bf(fmaxf(acc[i][j][v], 0.f));
                }
            }
        }
    } else {
        float* O = (float*)(kh ? Out1 : Out0);      // [(g*E+e)][CAP][N_total]
#pragma unroll
        for (int i = 0; i < 8; ++i) {
#pragma unroll
            for (int v = 0; v < 4; ++v) {
                int m_loc = wm * 128 + i * 16 + q * 4 + v;
                float* row = O + (((size_t)g * E_NUM + e) * CAP + m_loc) * N_total + n0 + wn * 32;
#pragma unroll
                for (int j = 0; j < 2; ++j) {
                    row[j * 16 + r] = acc[i][j][v];
                }
            }
        }
    }
}

// ---------------------------------------------------------------------------
// Kernel 6: combine — out[t,:] = w1*(eoA+eoB)[g,slot1,:] + w2*(eoA+eoB)[g,slot2,:]
// ---------------------------------------------------------------------------
__global__ void combine_kernel(const float* __restrict__ eoA, const float* __restrict__ eoB,
                               const int* __restrict__ slot1, const int* __restrict__ slot2,
                               const float* __restrict__ w1, const float* __restrict__ w2,
                               float* __restrict__ out, int G) {
    int t = blockIdx.x;
    int g = t / S_TOK;
    int tid = threadIdx.x;
    int s1 = slot1[t], s2 = slot2[t];
    float a = w1[t], b = w2[t];
    size_t gb = (size_t)g * E_NUM * CAP * M_DIM;
    const float* p1A = eoA + gb + (size_t)(s1 < 0 ? 0 : s1) * M_DIM;
    const float* p1B = eoB + gb + (size_t)(s1 < 0 ? 0 : s1) * M_DIM;
    const float* p2A = eoA + gb + (size_t)(s2 < 0 ? 0 : s2) * M_DIM;
    const float* p2B = eoB + gb + (size_t)(s2 < 0 ? 0 : s2) * M_DIM;
    for (int m = tid; m < M_DIM; m += 256) {
        float v = 0.f;
        if (s1 >= 0) v += a * (p1A[m] + p1B[m]);
        if (s2 >= 0) v += b * (p2A[m] + p2B[m]);
        out[(size_t)t * M_DIM + m] = v;
    }
}

// ---------------------------------------------------------------------------
extern "C" void kernel_launch(void* const* d_in, const int* in_sizes, int n_in,
                              void* d_out, int out_size, void* d_ws, size_t ws_size,
                              hipStream_t stream) {
    const float* x  = (const float*)d_in[0];
    const float* wg = (const float*)d_in[1];
    const float* wi = (const float*)d_in[2];
    const float* wo = (const float*)d_in[3];
    float* out = (float*)d_out;

    int ntok = in_sizes[0] / M_DIM;   // 4096
    int G = ntok / S_TOK;             // 2

    // workspace carve (256B aligned chunks)
    char* wsp = (char*)d_ws;
    auto carve = [&](size_t bytes) {
        void* p = (void*)wsp;
        wsp += (bytes + 255) & ~(size_t)255;
        return p;
    };
    int*   e1    = (int*)carve((size_t)ntok * 4);
    int*   e2    = (int*)carve((size_t)ntok * 4);
    float* g1    = (float*)carve((size_t)ntok * 4);
    float* g2    = (float*)carve((size_t)ntok * 4);
    int*   slot1 = (int*)carve((size_t)ntok * 4);
    int*   slot2 = (int*)carve((size_t)ntok * 4);
    float* w1    = (float*)carve((size_t)ntok * 4);
    float* w2    = (float*)carve((size_t)ntok * 4);
    int*   tfs   = (int*)carve((size_t)G * E_NUM * CAP * 4);
    unsigned short* xb  = (unsigned short*)carve((size_t)(ntok + 1) * M_DIM * 2);
    unsigned short* wiT = (unsigned short*)carve((size_t)E_NUM * H_DIM * M_DIM * 2);
    unsigned short* woT = (unsigned short*)carve((size_t)E_NUM * M_DIM * H_DIM * 2);
    unsigned short* h   = (unsigned short*)carve((size_t)E_NUM * G * CAP * H_DIM * 2);
    float* eo = (float*)carve((size_t)G * E_NUM * CAP * M_DIM * 4);
    // eoB (split-K half 2 of gemm2) aliases wiT: dead after gemm1; 75.5 > 25.2 MB.
    float* eoB = (float*)wiT;

    // 1: gating + x conversion (ntok+1 waves)
    gating_kernel<<<((ntok + 1) * 64 + 255) / 256, 256, 0, stream>>>(
        x, wg, e1, e2, g1, g2, xb, ntok);
    // 2: assignment
    assign_kernel<<<G, 1024, 0, stream>>>(e1, e2, g1, g2, slot1, slot2, w1, w2, tfs, G);
    // 3: both weight transposes in one launch (vectorized)
    transpose_conv_kernel<<<2 * NB_WI, 256, 0, stream>>>(wi, wiT, wo, woT);

    // 4: gemm1: h[z][CAP][H] = relu(gather(xb) @ wiT^T), K=768, 256x128 tiles
    mfma_gemm_kernel<M_DIM, true><<<(H_DIM / 128) * E_NUM * G, 512, 0, stream>>>(
        xb, wiT, tfs, h, h, G, H_DIM, M_DIM, 1);
    // 5: gemm2: eo(+eoB) = h @ woT^T, K=3072 split 2x1536, 256x128 tiles
    mfma_gemm_kernel<H_DIM / 2, false><<<(M_DIM / 128) * E_NUM * G * 2, 512, 0, stream>>>(
        h, woT, tfs, eo, eoB, G, M_DIM, H_DIM, 2);

    // 6: combine
    combine_kernel<<<ntok, 256, 0, stream>>>(eo, eoB, slot1, slot2, w1, w2, out, G);
}